// Round 1
// baseline (379.881 us; speedup 1.0000x reference)
//
#include <hip/hip_runtime.h>
#include <stdint.h>

#define TOKENS 65536
#define CDIM 384
#define NEXP 5
#define NPAIR 10
#define CAP 8192               // per-bucket capacity; E[cnt]=6554, sigma~77 -> 21-sigma margin
#define WE_STRIDE (CDIM * CDIM)

typedef __attribute__((ext_vector_type(8))) short short8;
typedef __attribute__((ext_vector_type(4))) float floatx4;

// unordered expert pair id p -> (a,b), a<b; p = a*4 - a*(a-1)/2 + (b-a-1)
__constant__ int PAIR_A[NPAIR] = {0, 0, 0, 0, 1, 1, 1, 2, 2, 3};
__constant__ int PAIR_B[NPAIR] = {1, 2, 3, 4, 2, 3, 4, 3, 4, 4};

__device__ inline unsigned short f2bf(float f) {
    union { float f; uint32_t u; } v; v.f = f;
    uint32_t r = v.u + 0x7fffu + ((v.u >> 16) & 1u);   // RNE for normal values
    return (unsigned short)(r >> 16);
}

__device__ inline void load_lds16(const void* g, void* l) {
    // async global->LDS, 16B/lane; dest = wave-uniform base + lane*16
    __builtin_amdgcn_global_load_lds((const __attribute__((address_space(1))) void*)g,
                                     (__attribute__((address_space(3))) void*)l, 16, 0, 0);
}

// ---------------- Kernel 1: router — token/thread, LDS x + LDS Wg, pipelined --------
// Compute path identical to verified dense version (fp64 accum, strict-> tie logic).
// Epilogue changed: instead of dense G[N][5], writes (token, g_lo, g_hi) into one of
// 10 expert-pair buckets via wave-aggregated atomics (<=10 atomics per wave).
__global__ __launch_bounds__(256) void router_kernel(const float* __restrict__ x,
                                                     const float* __restrict__ Wg,
                                                     int* __restrict__ cnt,
                                                     int* __restrict__ bidx,
                                                     float2* __restrict__ bgate) {
    __shared__ __align__(16) float xs[256 * 36];         // row stride 36 fl = 9 granules
    __shared__ __align__(16) float wgs[CDIM * NEXP];     // 7.7 KB
    int t = threadIdx.x;
    int tok0 = blockIdx.x * 256;
    for (int i = t; i < CDIM * NEXP; i += 256) wgs[i] = Wg[i];
    double p0 = 0, p1 = 0, p2 = 0, p3 = 0, p4 = 0;
    int lrow = t >> 3, c4 = (t & 7) * 4;
    const float* xbase = x + (size_t)tok0 * CDIM;
    float4 xr[8];
    #pragma unroll
    for (int i = 0; i < 8; ++i)
        xr[i] = *(const float4*)&xbase[(size_t)(lrow + 32 * i) * CDIM + c4];
    #pragma unroll
    for (int kc = 0; kc < 12; ++kc) {
        int k0 = kc * 32;
        __syncthreads();                                 // xs readers (kc-1) done
        #pragma unroll
        for (int i = 0; i < 8; ++i)
            *(float4*)&xs[(lrow + 32 * i) * 36 + c4] = xr[i];
        __syncthreads();                                 // xs[kc] ready (+ wgs on kc=0)
        if (kc < 11) {                                   // prefetch lands during compute
            #pragma unroll
            for (int i = 0; i < 8; ++i)
                xr[i] = *(const float4*)&xbase[(size_t)(lrow + 32 * i) * CDIM + k0 + 32 + c4];
        }
        #pragma unroll
        for (int jj = 0; jj < 8; ++jj) {
            float4 v = *(const float4*)&xs[t * 36 + jj * 4];
            const float4* wr = (const float4*)&wgs[(k0 + jj * 4) * NEXP];  // 16B-aligned
            float4 w0 = wr[0], w1 = wr[1], w2 = wr[2], w3 = wr[3], w4 = wr[4];
            p0 += (double)v.x * w0.x + (double)v.y * w1.y + (double)v.z * w2.z + (double)v.w * w3.w;
            p1 += (double)v.x * w0.y + (double)v.y * w1.z + (double)v.z * w2.w + (double)v.w * w4.x;
            p2 += (double)v.x * w0.z + (double)v.y * w1.w + (double)v.z * w3.x + (double)v.w * w4.y;
            p3 += (double)v.x * w0.w + (double)v.y * w2.x + (double)v.z * w3.y + (double)v.w * w4.z;
            p4 += (double)v.x * w1.x + (double)v.y * w2.y + (double)v.z * w3.z + (double)v.w * w4.w;
        }
    }
    double pa[NEXP] = {p0, p1, p2, p3, p4};
    int i0 = 0; double m0v = pa[0];
    #pragma unroll
    for (int e = 1; e < NEXP; ++e) if (pa[e] > m0v) { m0v = pa[e]; i0 = e; }  // strict >: lax.top_k ties
    int i1 = -1; double m1v = -1e300;
    #pragma unroll
    for (int e = 0; e < NEXP; ++e) if (e != i0 && pa[e] > m1v) { m1v = pa[e]; i1 = e; }
    float d  = (float)(m1v - m0v);
    float e1 = expf(d);
    float inv = 1.0f / (1.0f + e1);                      // gate of i0; gate of i1 = e1*inv

    int a  = i0 < i1 ? i0 : i1;
    int b2 = i0 < i1 ? i1 : i0;
    int p  = a * 4 - ((a * (a - 1)) >> 1) + (b2 - a - 1);
    float ga = (a == i0) ? inv : e1 * inv;               // gate of lower-indexed expert
    float gb = (a == i0) ? e1 * inv : inv;

    // wave-aggregated bucket append (Guideline 12)
    int lane = t & 63;
    unsigned long long below = (1ull << lane) - 1ull;
    int pos = 0;
    #pragma unroll
    for (int e = 0; e < NPAIR; ++e) {
        unsigned long long mask = __ballot(p == e);
        if (mask) {
            int leader = __ffsll((long long)mask) - 1;
            int basep = 0;
            if (lane == leader) basep = atomicAdd(&cnt[e], (int)__popcll(mask));
            basep = __shfl(basep, leader);
            if (p == e) pos = basep + (int)__popcll(mask & below);
        }
    }
    if (pos < CAP) {
        bidx[p * CAP + pos]  = tok0 + t;
        bgate[p * CAP + pos] = make_float2(ga, gb);
    }
}

// ---------------- Kernel 2: We[e][c][d] fp32 -> WeT[e][d][c] bf16 (tiled transpose) --
__global__ __launch_bounds__(256) void convert_we(const float* __restrict__ We,
                                                  unsigned short* __restrict__ WeT) {
    __shared__ float tile[64][65];
    int e  = blockIdx.z;
    int c0 = blockIdx.x * 64, d0 = blockIdx.y * 64;
    int t  = threadIdx.x;
    const float* src = We + (size_t)e * WE_STRIDE;
    int dr = t & 15, cr = t >> 4;
    for (int s = 0; s < 64; s += 16) {
        float4 v = *(const float4*)&src[(size_t)(c0 + cr + s) * CDIM + d0 + dr * 4];
        tile[cr + s][dr * 4 + 0] = v.x;
        tile[cr + s][dr * 4 + 1] = v.y;
        tile[cr + s][dr * 4 + 2] = v.z;
        tile[cr + s][dr * 4 + 3] = v.w;
    }
    __syncthreads();
    unsigned short* dst = WeT + (size_t)e * WE_STRIDE;
    int c4 = t & 15, drow = t >> 4;
    for (int s = 0; s < 64; s += 16) {
        int d = drow + s;
        ushort4 o;
        o.x = f2bf(tile[c4 * 4 + 0][d]);
        o.y = f2bf(tile[c4 * 4 + 1][d]);
        o.z = f2bf(tile[c4 * 4 + 2][d]);
        o.w = f2bf(tile[c4 * 4 + 3][d]);
        *(ushort4*)&dst[(size_t)(d0 + d) * CDIM + c0 + c4 * 4] = o;
    }
}

// ---------------- Kernel 3: grouped gathered GEMM over expert-pair buckets ----------
// Per block: (bucket p, m-tile of 128 gathered tokens, n-tile of 64 cols).
// Only the token's TWO selected experts are computed (2.5x FLOP cut vs dense-5).
// Structure inherited from the verified dense kernel: 128x64 tile, 8 waves 4(m)x2(n),
// A (bf16, VGPR-staged, swizzled) + B (async DMA) double-buffered, ONE sync per kc.
// Epilogue fuses gate-combine + bias + LeakyReLU; scatter row store (no atomics).
// LDS 32 KB, acc[2][2][2] -> low VGPR -> >=2 blocks/CU.
__global__ __launch_bounds__(512, 4) void moe_kernel(const float* __restrict__ x,
                                                     const unsigned short* __restrict__ WeT,
                                                     const int* __restrict__ cnt,
                                                     const int* __restrict__ bidx,
                                                     const float2* __restrict__ bgate,
                                                     const float* __restrict__ be,
                                                     float* __restrict__ out) {
    // XCD-chunk swizzle (grid 3840 = 8*480, bijective): n-tile siblings of one
    // (bucket, m-tile) A-panel land on the same XCD -> A reuse hits that XCD's L2.
    int bh  = blockIdx.x;
    int bid = (bh & 7) * ((NPAIR * 64 * 6) / 8) + (bh >> 3);
    int pq  = bid / 6;                    // p*64 + mt
    int nt  = bid - pq * 6;
    int p   = pq >> 6;
    int mt  = pq & 63;

    int nct = cnt[p];
    int m0  = mt * 128;
    if (m0 >= nct) return;                // block-uniform early exit (before any barrier)
    int valid = nct - m0; if (valid > 128) valid = 128;

    int ea = PAIR_A[p], eb = PAIR_B[p];
    int n0 = nt * 64;
    int t = threadIdx.x, lane = t & 63, wid = t >> 6;
    int wm = wid >> 1, wn = wid & 1;      // 4(m) x 2(n) waves
    int q = lane >> 4, cc = lane & 15;

    // granules (16B): A dbuf 0..1023 (512/buf), B dbuf 1024..2047 (512/buf) => 32 KB
    __shared__ __align__(16) unsigned short S[2048 * 8];

    floatx4 acc[2][2][2];                 // [expert a/b][m-sub][n-sub]
    #pragma unroll
    for (int e = 0; e < 2; ++e)
        #pragma unroll
        for (int i = 0; i < 2; ++i)
            #pragma unroll
            for (int j = 0; j < 2; ++j)
                acc[e][i][j] = (floatx4){0.0f, 0.0f, 0.0f, 0.0f};

    // B staging via DMA: 512 granules/kc, 1/thread. granule g=t: e=t>>8, r=(t&255)>>2,
    // phys slot gp=t&3 holds logical k-granule gl=(gp-(r>>1))&3 (conflict-free perm).
    int et = t >> 8, pe = t & 255, r = pe >> 2, gp = pe & 3;
    int gl = (gp - (r >> 1)) & 3;
    int esel = et ? eb : ea;
    const unsigned short* bsrc = WeT + (size_t)esel * WE_STRIDE + (size_t)(n0 + r) * CDIM + gl * 8;
    int bdst = wid * 64;                  // granule within B buf (+lane via DMA)

    // A staging: thread -> (gathered row, 16B piece), swizzled dest granule
    int srow = t >> 2, sp = t & 3;
    int arow = m0 + (srow < valid ? srow : valid - 1);   // clamp: ragged last tile
    int gi = bidx[p * CAP + arow];
    const float* xrow = x + (size_t)gi * CDIM + sp * 8;
    int agr = 4 * srow + ((sp + (srow >> 1)) & 3);       // + buf*512

    // fragment read bases (loop-invariant perm: (row>>1)&3 == (cc>>1)&3)
    int perm = (q + (cc >> 1)) & 3;
    int a_gr = 4 * (wm * 32 + cc) + perm;                // + 64*i + buf*512
    int b_gr = 1024 + 4 * (wn * 32 + cc) + perm;         // + 256*e + 64*j + buf*512

    // prologue: DMA B[0] into buf 0, then x[0] regs
    load_lds16(bsrc, S + (size_t)(1024 + bdst) * 8);
    float4 xreg[2][2];
    xreg[0][0] = *(const float4*)(xrow);
    xreg[0][1] = *(const float4*)(xrow + 4);

    #pragma unroll
    for (int kc = 0; kc < 12; ++kc) {
        int buf = kc & 1;
        // convert x[kc] -> As[buf]  (loads are one full iteration old)
        float4 a0 = xreg[buf][0], a1 = xreg[buf][1];
        short8 av;
        av[0] = f2bf(a0.x); av[1] = f2bf(a0.y); av[2] = f2bf(a0.z); av[3] = f2bf(a0.w);
        av[4] = f2bf(a1.x); av[5] = f2bf(a1.y); av[6] = f2bf(a1.z); av[7] = f2bf(a1.w);
        *(short8*)&S[(size_t)(buf * 512 + agr) * 8] = av;

        __syncthreads();   // drains DMA B[kc] (a full compute phase old) + As writes

        if (kc < 11) {     // issue next-chunk DMA + x prefetch AFTER the sync
            int nb = 1 - buf;
            int k1 = (kc + 1) * 32;
            load_lds16(bsrc + k1, S + (size_t)(1024 + nb * 512 + bdst) * 8);
            xreg[nb][0] = *(const float4*)(xrow + k1);
            xreg[nb][1] = *(const float4*)(xrow + k1 + 4);
        }

        int ao = buf * 512, bo = buf * 512;
        short8 af0 = *(const short8*)&S[(size_t)(ao + a_gr) * 8];
        short8 af1 = *(const short8*)&S[(size_t)(ao + a_gr + 64) * 8];
        short8 b00 = *(const short8*)&S[(size_t)(bo + b_gr) * 8];
        short8 b01 = *(const short8*)&S[(size_t)(bo + b_gr + 64) * 8];
        short8 b10 = *(const short8*)&S[(size_t)(bo + b_gr + 256) * 8];
        short8 b11 = *(const short8*)&S[(size_t)(bo + b_gr + 256 + 64) * 8];
        acc[0][0][0] = __builtin_amdgcn_mfma_f32_16x16x32_bf16(af0, b00, acc[0][0][0], 0, 0, 0);
        acc[0][1][0] = __builtin_amdgcn_mfma_f32_16x16x32_bf16(af1, b00, acc[0][1][0], 0, 0, 0);
        acc[0][0][1] = __builtin_amdgcn_mfma_f32_16x16x32_bf16(af0, b01, acc[0][0][1], 0, 0, 0);
        acc[0][1][1] = __builtin_amdgcn_mfma_f32_16x16x32_bf16(af1, b01, acc[0][1][1], 0, 0, 0);
        acc[1][0][0] = __builtin_amdgcn_mfma_f32_16x16x32_bf16(af0, b10, acc[1][0][0], 0, 0, 0);
        acc[1][1][0] = __builtin_amdgcn_mfma_f32_16x16x32_bf16(af1, b10, acc[1][1][0], 0, 0, 0);
        acc[1][0][1] = __builtin_amdgcn_mfma_f32_16x16x32_bf16(af0, b11, acc[1][0][1], 0, 0, 0);
        acc[1][1][1] = __builtin_amdgcn_mfma_f32_16x16x32_bf16(af1, b11, acc[1][1][1], 0, 0, 0);
    }

    // ---- epilogue: gates+indices to LDS, combine + bias + leaky, scatter store -----
    __syncthreads();
    float2* Gp = (float2*)S;                             // 128 * 8B = 1 KB
    int*    Ip = (int*)((char*)S + 1024);                // 128 * 4B
    if (t < 128) {
        int rr = m0 + (t < valid ? t : valid - 1);
        Gp[t] = bgate[p * CAP + rr];
        Ip[t] = bidx[p * CAP + rr];
    }
    float ba_[2], bb_[2];
    #pragma unroll
    for (int j = 0; j < 2; ++j) {
        int oc = n0 + wn * 32 + j * 16 + cc;
        ba_[j] = be[ea * CDIM + oc];
        bb_[j] = be[eb * CDIM + oc];
    }
    __syncthreads();

    #pragma unroll
    for (int i = 0; i < 2; ++i) {
        #pragma unroll
        for (int rr = 0; rr < 4; ++rr) {
            int trow = wm * 32 + i * 16 + q * 4 + rr;    // C/D: col=cc, row=q*4+rr
            if (trow < valid) {
                float2 g = Gp[trow];
                int gid  = Ip[trow];
                #pragma unroll
                for (int j = 0; j < 2; ++j) {
                    int oc = n0 + wn * 32 + j * 16 + cc;
                    float v = g.x * (acc[0][i][j][rr] + ba_[j])
                            + g.y * (acc[1][i][j][rr] + bb_[j]);
                    v = v > 0.0f ? v : 0.01f * v;
                    out[(size_t)gid * CDIM + oc] = v;
                }
            }
        }
    }
}

extern "C" void kernel_launch(void* const* d_in, const int* in_sizes, int n_in,
                              void* d_out, int out_size, void* d_ws, size_t ws_size,
                              hipStream_t stream) {
    const float* x  = (const float*)d_in[0];
    const float* Wg = (const float*)d_in[1];
    const float* We = (const float*)d_in[2];
    const float* be = (const float*)d_in[3];
    float* out = (float*)d_out;

    // ws layout: cnt[10] (pad 256B) | bidx 10*8192*4 | bgate 10*8192*8 | WeT 1.47MB
    //            total 2.34 MB (< previous 2.78 MB)
    int*            cnt   = (int*)d_ws;
    int*            bidx  = (int*)((char*)d_ws + 256);
    float2*         bgate = (float2*)((char*)d_ws + 256 + (size_t)NPAIR * CAP * 4);
    unsigned short* WeT   = (unsigned short*)((char*)d_ws + 256 + (size_t)NPAIR * CAP * 12);

    hipMemsetAsync(cnt, 0, NPAIR * sizeof(int), stream);   // graph-capturable
    router_kernel<<<TOKENS / 256, 256, 0, stream>>>(x, Wg, cnt, bidx, bgate);
    convert_we<<<dim3(6, 6, 5), 256, 0, stream>>>(We, WeT);
    moe_kernel<<<NPAIR * 64 * 6, 512, 0, stream>>>(x, WeT, cnt, bidx, bgate, be, out);
}

// Round 2
// 352.759 us; speedup vs baseline: 1.0769x; 1.0769x over previous
//
#include <hip/hip_runtime.h>
#include <stdint.h>

#define TOKENS 65536
#define CDIM 384
#define NEXP 5
#define NPAIR 10
#define CAP 8192               // per-bucket capacity; E[cnt]=6554, sigma~77 -> 21-sigma margin
#define WE_STRIDE (CDIM * CDIM)

typedef __attribute__((ext_vector_type(8))) short short8;
typedef __attribute__((ext_vector_type(4))) float floatx4;

// unordered expert pair id p -> (a,b), a<b; p = a*4 - a*(a-1)/2 + (b-a-1)
__constant__ int PAIR_A[NPAIR] = {0, 0, 0, 0, 1, 1, 1, 2, 2, 3};
__constant__ int PAIR_B[NPAIR] = {1, 2, 3, 4, 2, 3, 4, 3, 4, 4};

__device__ inline unsigned short f2bf(float f) {
    union { float f; uint32_t u; } v; v.f = f;
    uint32_t r = v.u + 0x7fffu + ((v.u >> 16) & 1u);   // RNE for normal values
    return (unsigned short)(r >> 16);
}

__device__ inline void load_lds16(const void* g, void* l) {
    // async global->LDS, 16B/lane; dest = wave-uniform base + lane*16
    __builtin_amdgcn_global_load_lds((const __attribute__((address_space(1))) void*)g,
                                     (__attribute__((address_space(3))) void*)l, 16, 0, 0);
}

// ---------------- Kernel 1: router v5 — 4 threads/token, fp64-exact, latency-fixed --
// Round-1 diagnosis: old router was 174us at VALUBusy 4.7% / Occupancy 11% -- 1024
// waves total (token/thread) cannot hide the serial fp64 chain. v5: wave w of each
// 256-thread block covers c-range [96w,96w+96) for 64 tokens (lane=token) -> 4096
// waves (16/CU). fp64 partials are order-independent (products exact, reassoc error
// ~1e-16), so selection is bit-equivalent to the verified v4. Wg staged in LDS at
// stride 8; inner-loop Wg reads are wave-uniform -> broadcast, conflict-free.
__global__ __launch_bounds__(256) void router_kernel(const float* __restrict__ x,
                                                     const float* __restrict__ Wg,
                                                     int* __restrict__ cnt,
                                                     int* __restrict__ bidx,
                                                     float2* __restrict__ bgate) {
    __shared__ __align__(16) float  wgs[CDIM * 8];      // padded stride 8, 12 KB
    __shared__ __align__(16) double part[4 * 64 * NEXP]; // 10 KB
    __shared__ __align__(16) double lg[64 * NEXP];       // 2.5 KB
    int t = threadIdx.x, lane = t & 63, w = t >> 6;
    int tok0 = blockIdx.x * 64;

    for (int i = t; i < CDIM * NEXP; i += 256) wgs[(i / NEXP) * 8 + (i % NEXP)] = Wg[i];
    __syncthreads();

    const float4* xb = (const float4*)(x + (size_t)(tok0 + lane) * CDIM + w * 96);
    double p0 = 0, p1 = 0, p2 = 0, p3 = 0, p4 = 0;
    #pragma unroll
    for (int i4 = 0; i4 < 24; ++i4) {
        float4 xv = xb[i4];
        #pragma unroll
        for (int u = 0; u < 4; ++u) {
            int c = w * 96 + i4 * 4 + u;                 // wave-uniform -> LDS broadcast
            float xe = (u == 0) ? xv.x : (u == 1) ? xv.y : (u == 2) ? xv.z : xv.w;
            float4 w03 = *(const float4*)&wgs[c * 8];    // 16B-aligned (stride 8)
            float  w4  = wgs[c * 8 + 4];
            double xd = (double)xe;
            p0 += xd * w03.x; p1 += xd * w03.y; p2 += xd * w03.z;
            p3 += xd * w03.w; p4 += xd * w4;
        }
    }
    double* pr = &part[(w * 64 + lane) * NEXP];
    pr[0] = p0; pr[1] = p1; pr[2] = p2; pr[3] = p3; pr[4] = p4;
    __syncthreads();

    // 320 items (64 tok x 5 experts); fixed w0+w1+w2+w3 order (fp64: order-exact)
    for (int item = t; item < 64 * NEXP; item += 256) {
        lg[item] = part[item] + part[320 + item] + part[640 + item] + part[960 + item];
    }
    __syncthreads();

    if (t < 64) {
        double pa[NEXP];
        #pragma unroll
        for (int e = 0; e < NEXP; ++e) pa[e] = lg[t * NEXP + e];
        int i0 = 0; double m0v = pa[0];
        #pragma unroll
        for (int e = 1; e < NEXP; ++e) if (pa[e] > m0v) { m0v = pa[e]; i0 = e; }  // strict >: lax.top_k ties
        int i1 = -1; double m1v = -1e300;
        #pragma unroll
        for (int e = 0; e < NEXP; ++e) if (e != i0 && pa[e] > m1v) { m1v = pa[e]; i1 = e; }
        float d  = (float)(m1v - m0v);
        float e1 = expf(d);
        float inv = 1.0f / (1.0f + e1);                  // gate of i0; gate of i1 = e1*inv

        int a  = i0 < i1 ? i0 : i1;
        int b2 = i0 < i1 ? i1 : i0;
        int p  = a * 4 - ((a * (a - 1)) >> 1) + (b2 - a - 1);
        float ga = (a == i0) ? inv : e1 * inv;           // gate of lower-indexed expert
        float gb = (a == i0) ? e1 * inv : inv;

        // wave-aggregated bucket append (wave 0 only; all 64 lanes active here)
        unsigned long long below = (1ull << lane) - 1ull;
        int pos = 0;
        #pragma unroll
        for (int e = 0; e < NPAIR; ++e) {
            unsigned long long mask = __ballot(p == e);
            if (mask) {
                int leader = __ffsll((long long)mask) - 1;
                int basep = 0;
                if (lane == leader) basep = atomicAdd(&cnt[e], (int)__popcll(mask));
                basep = __shfl(basep, leader);
                if (p == e) pos = basep + (int)__popcll(mask & below);
            }
        }
        if (pos < CAP) {
            bidx[p * CAP + pos]  = tok0 + t;
            bgate[p * CAP + pos] = make_float2(ga, gb);
        }
    }
}

// ---------------- Kernel 2: We[e][c][d] fp32 -> WeT[e][d][c] bf16 (tiled transpose) --
__global__ __launch_bounds__(256) void convert_we(const float* __restrict__ We,
                                                  unsigned short* __restrict__ WeT) {
    __shared__ float tile[64][65];
    int e  = blockIdx.z;
    int c0 = blockIdx.x * 64, d0 = blockIdx.y * 64;
    int t  = threadIdx.x;
    const float* src = We + (size_t)e * WE_STRIDE;
    int dr = t & 15, cr = t >> 4;
    for (int s = 0; s < 64; s += 16) {
        float4 v = *(const float4*)&src[(size_t)(c0 + cr + s) * CDIM + d0 + dr * 4];
        tile[cr + s][dr * 4 + 0] = v.x;
        tile[cr + s][dr * 4 + 1] = v.y;
        tile[cr + s][dr * 4 + 2] = v.z;
        tile[cr + s][dr * 4 + 3] = v.w;
    }
    __syncthreads();
    unsigned short* dst = WeT + (size_t)e * WE_STRIDE;
    int c4 = t & 15, drow = t >> 4;
    for (int s = 0; s < 64; s += 16) {
        int d = drow + s;
        ushort4 o;
        o.x = f2bf(tile[c4 * 4 + 0][d]);
        o.y = f2bf(tile[c4 * 4 + 1][d]);
        o.z = f2bf(tile[c4 * 4 + 2][d]);
        o.w = f2bf(tile[c4 * 4 + 3][d]);
        *(ushort4*)&dst[(size_t)(d0 + d) * CDIM + c0 + c4 * 4] = o;
    }
}

// ---------------- Kernel 3: grouped gathered GEMM over expert-pair buckets ----------
// (unchanged from round 0 -- left untouched so round-2 counters isolate it cleanly)
__global__ __launch_bounds__(512, 4) void moe_kernel(const float* __restrict__ x,
                                                     const unsigned short* __restrict__ WeT,
                                                     const int* __restrict__ cnt,
                                                     const int* __restrict__ bidx,
                                                     const float2* __restrict__ bgate,
                                                     const float* __restrict__ be,
                                                     float* __restrict__ out) {
    int bh  = blockIdx.x;
    int bid = (bh & 7) * ((NPAIR * 64 * 6) / 8) + (bh >> 3);
    int pq  = bid / 6;                    // p*64 + mt
    int nt  = bid - pq * 6;
    int p   = pq >> 6;
    int mt  = pq & 63;

    int nct = cnt[p];
    int m0  = mt * 128;
    if (m0 >= nct) return;                // block-uniform early exit (before any barrier)
    int valid = nct - m0; if (valid > 128) valid = 128;

    int ea = PAIR_A[p], eb = PAIR_B[p];
    int n0 = nt * 64;
    int t = threadIdx.x, lane = t & 63, wid = t >> 6;
    int wm = wid >> 1, wn = wid & 1;      // 4(m) x 2(n) waves
    int q = lane >> 4, cc = lane & 15;

    // granules (16B): A dbuf 0..1023 (512/buf), B dbuf 1024..2047 (512/buf) => 32 KB
    __shared__ __align__(16) unsigned short S[2048 * 8];

    floatx4 acc[2][2][2];                 // [expert a/b][m-sub][n-sub]
    #pragma unroll
    for (int e = 0; e < 2; ++e)
        #pragma unroll
        for (int i = 0; i < 2; ++i)
            #pragma unroll
            for (int j = 0; j < 2; ++j)
                acc[e][i][j] = (floatx4){0.0f, 0.0f, 0.0f, 0.0f};

    // B staging via DMA: 512 granules/kc, 1/thread
    int et = t >> 8, pe = t & 255, r = pe >> 2, gp = pe & 3;
    int gl = (gp - (r >> 1)) & 3;
    int esel = et ? eb : ea;
    const unsigned short* bsrc = WeT + (size_t)esel * WE_STRIDE + (size_t)(n0 + r) * CDIM + gl * 8;
    int bdst = wid * 64;                  // granule within B buf (+lane via DMA)

    // A staging: thread -> (gathered row, 16B piece), swizzled dest granule
    int srow = t >> 2, sp = t & 3;
    int arow = m0 + (srow < valid ? srow : valid - 1);   // clamp: ragged last tile
    int gi = bidx[p * CAP + arow];
    const float* xrow = x + (size_t)gi * CDIM + sp * 8;
    int agr = 4 * srow + ((sp + (srow >> 1)) & 3);       // + buf*512

    // fragment read bases (loop-invariant perm: (row>>1)&3 == (cc>>1)&3)
    int perm = (q + (cc >> 1)) & 3;
    int a_gr = 4 * (wm * 32 + cc) + perm;                // + 64*i + buf*512
    int b_gr = 1024 + 4 * (wn * 32 + cc) + perm;         // + 256*e + 64*j + buf*512

    // prologue: DMA B[0] into buf 0, then x[0] regs
    load_lds16(bsrc, S + (size_t)(1024 + bdst) * 8);
    float4 xreg[2][2];
    xreg[0][0] = *(const float4*)(xrow);
    xreg[0][1] = *(const float4*)(xrow + 4);

    #pragma unroll
    for (int kc = 0; kc < 12; ++kc) {
        int buf = kc & 1;
        // convert x[kc] -> As[buf]  (loads are one full iteration old)
        float4 a0 = xreg[buf][0], a1 = xreg[buf][1];
        short8 av;
        av[0] = f2bf(a0.x); av[1] = f2bf(a0.y); av[2] = f2bf(a0.z); av[3] = f2bf(a0.w);
        av[4] = f2bf(a1.x); av[5] = f2bf(a1.y); av[6] = f2bf(a1.z); av[7] = f2bf(a1.w);
        *(short8*)&S[(size_t)(buf * 512 + agr) * 8] = av;

        __syncthreads();   // drains DMA B[kc] (a full compute phase old) + As writes

        if (kc < 11) {     // issue next-chunk DMA + x prefetch AFTER the sync
            int nb = 1 - buf;
            int k1 = (kc + 1) * 32;
            load_lds16(bsrc + k1, S + (size_t)(1024 + nb * 512 + bdst) * 8);
            xreg[nb][0] = *(const float4*)(xrow + k1);
            xreg[nb][1] = *(const float4*)(xrow + k1 + 4);
        }

        int ao = buf * 512, bo = buf * 512;
        short8 af0 = *(const short8*)&S[(size_t)(ao + a_gr) * 8];
        short8 af1 = *(const short8*)&S[(size_t)(ao + a_gr + 64) * 8];
        short8 b00 = *(const short8*)&S[(size_t)(bo + b_gr) * 8];
        short8 b01 = *(const short8*)&S[(size_t)(bo + b_gr + 64) * 8];
        short8 b10 = *(const short8*)&S[(size_t)(bo + b_gr + 256) * 8];
        short8 b11 = *(const short8*)&S[(size_t)(bo + b_gr + 256 + 64) * 8];
        acc[0][0][0] = __builtin_amdgcn_mfma_f32_16x16x32_bf16(af0, b00, acc[0][0][0], 0, 0, 0);
        acc[0][1][0] = __builtin_amdgcn_mfma_f32_16x16x32_bf16(af1, b00, acc[0][1][0], 0, 0, 0);
        acc[0][0][1] = __builtin_amdgcn_mfma_f32_16x16x32_bf16(af0, b01, acc[0][0][1], 0, 0, 0);
        acc[0][1][1] = __builtin_amdgcn_mfma_f32_16x16x32_bf16(af1, b01, acc[0][1][1], 0, 0, 0);
        acc[1][0][0] = __builtin_amdgcn_mfma_f32_16x16x32_bf16(af0, b10, acc[1][0][0], 0, 0, 0);
        acc[1][1][0] = __builtin_amdgcn_mfma_f32_16x16x32_bf16(af1, b10, acc[1][1][0], 0, 0, 0);
        acc[1][0][1] = __builtin_amdgcn_mfma_f32_16x16x32_bf16(af0, b11, acc[1][0][1], 0, 0, 0);
        acc[1][1][1] = __builtin_amdgcn_mfma_f32_16x16x32_bf16(af1, b11, acc[1][1][1], 0, 0, 0);
    }

    // ---- epilogue: gates+indices to LDS, combine + bias + leaky, scatter store -----
    __syncthreads();
    float2* Gp = (float2*)S;                             // 128 * 8B = 1 KB
    int*    Ip = (int*)((char*)S + 1024);                // 128 * 4B
    if (t < 128) {
        int rr = m0 + (t < valid ? t : valid - 1);
        Gp[t] = bgate[p * CAP + rr];
        Ip[t] = bidx[p * CAP + rr];
    }
    float ba_[2], bb_[2];
    #pragma unroll
    for (int j = 0; j < 2; ++j) {
        int oc = n0 + wn * 32 + j * 16 + cc;
        ba_[j] = be[ea * CDIM + oc];
        bb_[j] = be[eb * CDIM + oc];
    }
    __syncthreads();

    #pragma unroll
    for (int i = 0; i < 2; ++i) {
        #pragma unroll
        for (int rr = 0; rr < 4; ++rr) {
            int trow = wm * 32 + i * 16 + q * 4 + rr;    // C/D: col=cc, row=q*4+rr
            if (trow < valid) {
                float2 g = Gp[trow];
                int gid  = Ip[trow];
                #pragma unroll
                for (int j = 0; j < 2; ++j) {
                    int oc = n0 + wn * 32 + j * 16 + cc;
                    float v = g.x * (acc[0][i][j][rr] + ba_[j])
                            + g.y * (acc[1][i][j][rr] + bb_[j]);
                    v = v > 0.0f ? v : 0.01f * v;
                    out[(size_t)gid * CDIM + oc] = v;
                }
            }
        }
    }
}

extern "C" void kernel_launch(void* const* d_in, const int* in_sizes, int n_in,
                              void* d_out, int out_size, void* d_ws, size_t ws_size,
                              hipStream_t stream) {
    const float* x  = (const float*)d_in[0];
    const float* Wg = (const float*)d_in[1];
    const float* We = (const float*)d_in[2];
    const float* be = (const float*)d_in[3];
    float* out = (float*)d_out;

    // ws layout: cnt[10] (pad 256B) | bidx 10*8192*4 | bgate 10*8192*8 | WeT 1.47MB
    int*            cnt   = (int*)d_ws;
    int*            bidx  = (int*)((char*)d_ws + 256);
    float2*         bgate = (float2*)((char*)d_ws + 256 + (size_t)NPAIR * CAP * 4);
    unsigned short* WeT   = (unsigned short*)((char*)d_ws + 256 + (size_t)NPAIR * CAP * 12);

    hipMemsetAsync(cnt, 0, NPAIR * sizeof(int), stream);   // graph-capturable
    router_kernel<<<TOKENS / 64, 256, 0, stream>>>(x, Wg, cnt, bidx, bgate);
    convert_we<<<dim3(6, 6, 5), 256, 0, stream>>>(We, WeT);
    moe_kernel<<<NPAIR * 64 * 6, 512, 0, stream>>>(x, WeT, cnt, bidx, bgate, be, out);
}

// Round 4
// 250.243 us; speedup vs baseline: 1.5180x; 1.4097x over previous
//
#include <hip/hip_runtime.h>
#include <stdint.h>

#define TOKENS 65536
#define CDIM 384
#define NEXP 5
#define NPAIR 10
#define CAP 8192               // per-bucket capacity; E[cnt]=6554, sigma~77 -> 21-sigma margin
#define NBLK 1024              // router blocks (64 tokens each)
#define WE_STRIDE (CDIM * CDIM)

typedef __attribute__((ext_vector_type(8))) short short8;
typedef __attribute__((ext_vector_type(4))) float floatx4;

// unordered expert pair id p -> (a,b), a<b; p = a*4 - a*(a-1)/2 + (b-a-1)
__constant__ int PAIR_A[NPAIR] = {0, 0, 0, 0, 1, 1, 1, 2, 2, 3};
__constant__ int PAIR_B[NPAIR] = {1, 2, 3, 4, 2, 3, 4, 3, 4, 4};

__device__ inline unsigned short f2bf(float f) {
    union { float f; uint32_t u; } v; v.f = f;
    uint32_t r = v.u + 0x7fffu + ((v.u >> 16) & 1u);   // RNE for normal values
    return (unsigned short)(r >> 16);
}

__device__ inline void load_lds16(const void* g, void* l) {
    // async global->LDS, 16B/lane; dest = wave-uniform base + lane*16
    __builtin_amdgcn_global_load_lds((const __attribute__((address_space(1))) void*)g,
                                     (__attribute__((address_space(3))) void*)l, 16, 0, 0);
}

// ---------------- Kernel 1a: router — compute + per-block ballot histogram ----------
// Round-2 diagnosis: 10240 device atomics to ONE cache line (cnt[0..9]) serialized at
// ~15ns each ~= the whole 156us (VALUBusy 4.9% x 156us = 7.6us of real work). v6 is
// atomic-FREE: per-block counts via ballot -> blkcnt[p][blk]; per-token (pair, rank)
// records; positions resolved by a scan + scatter pass. fp64 compute path unchanged.
__global__ __launch_bounds__(256) void router_kernel(const float* __restrict__ x,
                                                     const float* __restrict__ Wg,
                                                     int* __restrict__ blkcnt,
                                                     int* __restrict__ tmeta,
                                                     float2* __restrict__ tgate) {
    __shared__ __align__(16) float  wgs[CDIM * 8];       // padded stride 8, 12 KB
    __shared__ __align__(16) double part[4 * 64 * NEXP]; // 10 KB
    __shared__ __align__(16) double lg[64 * NEXP];       // 2.5 KB
    int t = threadIdx.x, lane = t & 63, w = t >> 6;
    int tok0 = blockIdx.x * 64;

    for (int i = t; i < CDIM * NEXP; i += 256) wgs[(i / NEXP) * 8 + (i % NEXP)] = Wg[i];
    __syncthreads();

    const float4* xb = (const float4*)(x + (size_t)(tok0 + lane) * CDIM + w * 96);
    double p0 = 0, p1 = 0, p2 = 0, p3 = 0, p4 = 0;
    #pragma unroll
    for (int i4 = 0; i4 < 24; ++i4) {
        float4 xv = xb[i4];
        #pragma unroll
        for (int u = 0; u < 4; ++u) {
            int c = w * 96 + i4 * 4 + u;                 // wave-uniform -> LDS broadcast
            float xe = (u == 0) ? xv.x : (u == 1) ? xv.y : (u == 2) ? xv.z : xv.w;
            float4 w03 = *(const float4*)&wgs[c * 8];    // 16B-aligned (stride 8)
            float  w4  = wgs[c * 8 + 4];
            double xd = (double)xe;
            p0 += xd * w03.x; p1 += xd * w03.y; p2 += xd * w03.z;
            p3 += xd * w03.w; p4 += xd * w4;
        }
    }
    double* pr = &part[(w * 64 + lane) * NEXP];
    pr[0] = p0; pr[1] = p1; pr[2] = p2; pr[3] = p3; pr[4] = p4;
    __syncthreads();

    for (int item = t; item < 64 * NEXP; item += 256) {
        lg[item] = part[item] + part[320 + item] + part[640 + item] + part[960 + item];
    }
    __syncthreads();

    if (t < 64) {                                        // wave 0: whole block's tokens
        double pa[NEXP];
        #pragma unroll
        for (int e = 0; e < NEXP; ++e) pa[e] = lg[t * NEXP + e];
        int i0 = 0; double m0v = pa[0];
        #pragma unroll
        for (int e = 1; e < NEXP; ++e) if (pa[e] > m0v) { m0v = pa[e]; i0 = e; }  // strict >: lax.top_k ties
        int i1 = -1; double m1v = -1e300;
        #pragma unroll
        for (int e = 0; e < NEXP; ++e) if (e != i0 && pa[e] > m1v) { m1v = pa[e]; i1 = e; }
        float d  = (float)(m1v - m0v);
        float e1 = expf(d);
        float inv = 1.0f / (1.0f + e1);                  // gate of i0; gate of i1 = e1*inv

        int a  = i0 < i1 ? i0 : i1;
        int b2 = i0 < i1 ? i1 : i0;
        int p  = a * 4 - ((a * (a - 1)) >> 1) + (b2 - a - 1);
        float ga = (a == i0) ? inv : e1 * inv;           // gate of lower-indexed expert
        float gb = (a == i0) ? e1 * inv : inv;

        unsigned long long below = (1ull << lane) - 1ull;
        int myrank = 0, myh = 0;
        #pragma unroll
        for (int e = 0; e < NPAIR; ++e) {
            unsigned long long mask = __ballot(p == e);
            if (p == e)    myrank = (int)__popcll(mask & below);
            if (lane == e) myh    = (int)__popcll(mask);
        }
        tmeta[tok0 + lane] = p | (myrank << 8);          // p<10, rank<64
        tgate[tok0 + lane] = make_float2(ga, gb);
        if (lane < NPAIR) blkcnt[lane * NBLK + blockIdx.x] = myh;
    }
}

// ---------------- Kernel 1b: per-pair exclusive prefix over 1024 block counts -------
// One block per pair. Deterministic, contention-free replacement for the atomics.
__global__ __launch_bounds__(256) void scan_kernel(const int* __restrict__ blkcnt,
                                                   int* __restrict__ bbase,
                                                   int* __restrict__ cnt) {
    __shared__ int wsum[4];
    int p = blockIdx.x, t = threadIdx.x, lane = t & 63, w = t >> 6;
    int4 v = ((const int4*)(blkcnt + p * NBLK))[t];      // blocks 4t..4t+3
    int s0 = v.x, s1 = s0 + v.y, s2 = s1 + v.z, s3 = s2 + v.w;
    int ws = s3;                                         // wave-inclusive scan of totals
    #pragma unroll
    for (int d = 1; d < 64; d <<= 1) {
        int o = __shfl_up(ws, d);
        if (lane >= d) ws += o;
    }
    if (lane == 63) wsum[w] = ws;
    __syncthreads();
    int woff = 0;
    for (int k = 0; k < w; ++k) woff += wsum[k];
    int excl = woff + ws - s3;                           // exclusive prefix before block 4t
    int4 b; b.x = excl; b.y = excl + s0; b.z = excl + s1; b.w = excl + s2;
    ((int4*)(bbase + p * NBLK))[t] = b;
    if (t == 255) cnt[p] = excl + s3;
}

// ---------------- Kernel 1c: scatter token ids to bucket positions ------------------
__global__ __launch_bounds__(256) void scatter_kernel(const int* __restrict__ tmeta,
                                                      const int* __restrict__ bbase,
                                                      int* __restrict__ bidx) {
    int tok = blockIdx.x * 256 + threadIdx.x;
    int meta = tmeta[tok];
    int p = meta & 255, rank = meta >> 8;
    int pos = bbase[p * NBLK + (tok >> 6)] + rank;
    if (pos < CAP) bidx[p * CAP + pos] = tok;
}

// ---------------- Kernel 2: We[e][c][d] fp32 -> WeT[e][d][c] bf16 (tiled transpose) --
__global__ __launch_bounds__(256) void convert_we(const float* __restrict__ We,
                                                  unsigned short* __restrict__ WeT) {
    __shared__ float tile[64][65];
    int e  = blockIdx.z;
    int c0 = blockIdx.x * 64, d0 = blockIdx.y * 64;
    int t  = threadIdx.x;
    const float* src = We + (size_t)e * WE_STRIDE;
    int dr = t & 15, cr = t >> 4;
    for (int s = 0; s < 64; s += 16) {
        float4 v = *(const float4*)&src[(size_t)(c0 + cr + s) * CDIM + d0 + dr * 4];
        tile[cr + s][dr * 4 + 0] = v.x;
        tile[cr + s][dr * 4 + 1] = v.y;
        tile[cr + s][dr * 4 + 2] = v.z;
        tile[cr + s][dr * 4 + 3] = v.w;
    }
    __syncthreads();
    unsigned short* dst = WeT + (size_t)e * WE_STRIDE;
    int c4 = t & 15, drow = t >> 4;
    for (int s = 0; s < 64; s += 16) {
        int d = drow + s;
        ushort4 o;
        o.x = f2bf(tile[c4 * 4 + 0][d]);
        o.y = f2bf(tile[c4 * 4 + 1][d]);
        o.z = f2bf(tile[c4 * 4 + 2][d]);
        o.w = f2bf(tile[c4 * 4 + 3][d]);
        *(ushort4*)&dst[(size_t)(d0 + d) * CDIM + c0 + c4 * 4] = o;
    }
}

// ---------------- Kernel 3: grouped gathered GEMM, 128x128 tile ---------------------
// Round-2 diagnosis: sparse moe stayed ~150us despite 2.5x FLOP cut -> barrier-
// overhead-bound (8 MFMA per full-drain sync). v2: n-tile 64->128 doubles per-barrier
// MFMA work (16 MFMA + 10 b128 reads/kc), halves block count (A-panels fetched 3x not
// 6x). LDS 48KB, acc[2][2][4]; schedule (one sync per kc, DMA issued post-sync one
// phase ahead) inherited unchanged from the verified structure.
__global__ __launch_bounds__(512, 4) void moe_kernel(const float* __restrict__ x,
                                                     const unsigned short* __restrict__ WeT,
                                                     const int* __restrict__ cnt,
                                                     const int* __restrict__ bidx,
                                                     const float2* __restrict__ tgate,
                                                     const float* __restrict__ be,
                                                     float* __restrict__ out) {
    // grid 1920 = 8*240: bijective XCD-chunk swizzle; consecutive bids (same A/B
    // panels) stay on one XCD's L2.
    int bh  = blockIdx.x;
    int bid = (bh & 7) * 240 + (bh >> 3);
    int pq  = bid / 3;                    // p*64 + mt
    int nt  = bid - pq * 3;
    int p   = pq >> 6;
    int mt  = pq & 63;

    int nct = cnt[p];
    int m0  = mt * 128;
    if (m0 >= nct) return;                // block-uniform early exit (before any barrier)
    int valid = nct - m0; if (valid > 128) valid = 128;

    int ea = PAIR_A[p], eb = PAIR_B[p];
    int n0 = nt * 128;
    int t = threadIdx.x, lane = t & 63, wid = t >> 6;
    int wm = wid >> 1, wn = wid & 1;      // 4(m) x 2(n) waves -> wave tile 32x64
    int q = lane >> 4, cc = lane & 15;

    // granules (16B): A dbuf 0..1023 (512/buf), B dbuf 1024..3071 (1024/buf) => 48 KB
    __shared__ __align__(16) unsigned short S[3072 * 8];

    floatx4 acc[2][2][4];                 // [expert a/b][m-sub][n-sub]
    #pragma unroll
    for (int e = 0; e < 2; ++e)
        #pragma unroll
        for (int i = 0; i < 2; ++i)
            #pragma unroll
            for (int j = 0; j < 4; ++j)
                acc[e][i][j] = (floatx4){0.0f, 0.0f, 0.0f, 0.0f};

    // B staging via DMA: 1024 granules/kc, 2/thread (rep0 = expert a, rep1 = expert b)
    int rrow = t >> 2, gp = t & 3;
    int gl = (gp - (rrow >> 1)) & 3;      // conflict-free k-granule perm (verified)
    const unsigned short* bsrcA = WeT + (size_t)ea * WE_STRIDE + (size_t)(n0 + rrow) * CDIM + gl * 8;
    const unsigned short* bsrcB = WeT + (size_t)eb * WE_STRIDE + (size_t)(n0 + rrow) * CDIM + gl * 8;
    int bdstA = 1024 + wid * 64;          // + buf*1024 (+lane via DMA)
    int bdstB = 1024 + 512 + wid * 64;

    // A staging: thread -> (gathered row, 16B piece), swizzled dest granule
    int srow = t >> 2, sp = t & 3;
    int arow = m0 + (srow < valid ? srow : valid - 1);   // clamp: ragged last tile
    int gi = bidx[p * CAP + arow];
    const float* xrow = x + (size_t)gi * CDIM + sp * 8;
    int agr = 4 * srow + ((sp + (srow >> 1)) & 3);       // + buf*512

    // fragment read bases (loop-invariant perm: (row>>1)&3 == (cc>>1)&3)
    int perm = (q + (cc >> 1)) & 3;
    int a_gr = 4 * (wm * 32 + cc) + perm;                // + 64*i + buf*512
    int b_gr = 1024 + 4 * (wn * 64 + cc) + perm;         // + 512*e + 64*j + buf*1024

    // prologue: DMA B[0] into buf 0, then x[0] regs
    load_lds16(bsrcA, S + (size_t)bdstA * 8);
    load_lds16(bsrcB, S + (size_t)bdstB * 8);
    float4 xreg[2][2];
    xreg[0][0] = *(const float4*)(xrow);
    xreg[0][1] = *(const float4*)(xrow + 4);

    #pragma unroll
    for (int kc = 0; kc < 12; ++kc) {
        int buf = kc & 1;
        // convert x[kc] -> As[buf]  (loads are one full iteration old)
        float4 a0 = xreg[buf][0], a1 = xreg[buf][1];
        short8 av;
        av[0] = f2bf(a0.x); av[1] = f2bf(a0.y); av[2] = f2bf(a0.z); av[3] = f2bf(a0.w);
        av[4] = f2bf(a1.x); av[5] = f2bf(a1.y); av[6] = f2bf(a1.z); av[7] = f2bf(a1.w);
        *(short8*)&S[(size_t)(buf * 512 + agr) * 8] = av;

        __syncthreads();   // drains DMA B[kc] (a full compute phase old) + As writes

        if (kc < 11) {     // issue next-chunk DMA + x prefetch AFTER the sync
            int nb = 1 - buf;
            int k1 = (kc + 1) * 32;
            load_lds16(bsrcA + k1, S + (size_t)(nb * 1024 + bdstA) * 8);
            load_lds16(bsrcB + k1, S + (size_t)(nb * 1024 + bdstB) * 8);
            xreg[nb][0] = *(const float4*)(xrow + k1);
            xreg[nb][1] = *(const float4*)(xrow + k1 + 4);
        }

        int ao = buf * 512, bo = buf * 1024;
        short8 af0 = *(const short8*)&S[(size_t)(ao + a_gr) * 8];
        short8 af1 = *(const short8*)&S[(size_t)(ao + a_gr + 64) * 8];
        #pragma unroll
        for (int e = 0; e < 2; ++e) {
            #pragma unroll
            for (int j = 0; j < 4; ++j) {
                short8 bf = *(const short8*)&S[(size_t)(bo + b_gr + e * 512 + j * 64) * 8];
                acc[e][0][j] = __builtin_amdgcn_mfma_f32_16x16x32_bf16(af0, bf, acc[e][0][j], 0, 0, 0);
                acc[e][1][j] = __builtin_amdgcn_mfma_f32_16x16x32_bf16(af1, bf, acc[e][1][j], 0, 0, 0);
            }
        }
    }

    // ---- epilogue: gates+indices to LDS, combine + bias + leaky, scatter store -----
    __syncthreads();
    float2* Gp = (float2*)S;                             // 128 * 8B = 1 KB
    int*    Ip = (int*)((char*)S + 1024);                // 128 * 4B
    if (t < 128) {
        int rr = m0 + (t < valid ? t : valid - 1);
        int gid = bidx[p * CAP + rr];
        Ip[t] = gid;
        Gp[t] = tgate[gid];                              // token-indexed gates (no bgate)
    }
    float ba_[4], bb_[4];
    #pragma unroll
    for (int j = 0; j < 4; ++j) {
        int oc = n0 + wn * 64 + j * 16 + cc;
        ba_[j] = be[ea * CDIM + oc];
        bb_[j] = be[eb * CDIM + oc];
    }
    __syncthreads();

    #pragma unroll
    for (int i = 0; i < 2; ++i) {
        #pragma unroll
        for (int rr4 = 0; rr4 < 4; ++rr4) {
            int trow = wm * 32 + i * 16 + q * 4 + rr4;   // C/D: col=cc, row=q*4+rr4
            if (trow < valid) {
                float2 g = Gp[trow];
                int gid  = Ip[trow];
                #pragma unroll
                for (int j = 0; j < 4; ++j) {
                    int oc = n0 + wn * 64 + j * 16 + cc;
                    float v = g.x * (acc[0][i][j][rr4] + ba_[j])
                            + g.y * (acc[1][i][j][rr4] + bb_[j]);
                    v = v > 0.0f ? v : 0.01f * v;
                    out[(size_t)gid * CDIM + oc] = v;
                }
            }
        }
    }
}

extern "C" void kernel_launch(void* const* d_in, const int* in_sizes, int n_in,
                              void* d_out, int out_size, void* d_ws, size_t ws_size,
                              hipStream_t stream) {
    const float* x  = (const float*)d_in[0];
    const float* Wg = (const float*)d_in[1];
    const float* We = (const float*)d_in[2];
    const float* be = (const float*)d_in[3];
    float* out = (float*)d_out;

    // ws layout (16B-aligned sections), total ~2.67 MB:
    //   cnt[10]            @ 0       (pad 256)
    //   bidx  10*8192*4    @ 256         = 327680
    //   blkcnt 10*1024*4   @ 327936      = 40960
    //   bbase  10*1024*4   @ 368896      = 40960
    //   tmeta  65536*4     @ 409856      = 262144
    //   tgate  65536*8     @ 672000      = 524288
    //   WeT    5*384*384*2 @ 1196288     = 1474560
    char* ws = (char*)d_ws;
    int*            cnt    = (int*)ws;
    int*            bidx   = (int*)(ws + 256);
    int*            blkcnt = (int*)(ws + 327936);
    int*            bbase  = (int*)(ws + 368896);
    int*            tmeta  = (int*)(ws + 409856);
    float2*         tgate  = (float2*)(ws + 672000);
    unsigned short* WeT    = (unsigned short*)(ws + 1196288);

    router_kernel<<<NBLK, 256, 0, stream>>>(x, Wg, blkcnt, tmeta, tgate);
    scan_kernel<<<NPAIR, 256, 0, stream>>>(blkcnt, bbase, cnt);
    scatter_kernel<<<TOKENS / 256, 256, 0, stream>>>(tmeta, bbase, bidx);
    convert_we<<<dim3(6, 6, 5), 256, 0, stream>>>(We, WeT);
    moe_kernel<<<NPAIR * 64 * 3, 512, 0, stream>>>(x, WeT, cnt, bidx, tgate, be, out);
}

// Round 5
// 246.897 us; speedup vs baseline: 1.5386x; 1.0136x over previous
//
#include <hip/hip_runtime.h>
#include <stdint.h>

#define TOKENS 65536
#define CDIM 384
#define NEXP 5
#define NPAIR 10
#define CAP 8192               // per-bucket capacity; E[cnt]=6554, sigma~77 -> 21-sigma margin
#define NBLK 1024              // router blocks (64 tokens each)
#define WE_STRIDE (CDIM * CDIM)

typedef __attribute__((ext_vector_type(8))) short short8;
typedef __attribute__((ext_vector_type(4))) float floatx4;

// unordered expert pair id p -> (a,b), a<b; p = a*4 - a*(a-1)/2 + (b-a-1)
__constant__ int PAIR_A[NPAIR] = {0, 0, 0, 0, 1, 1, 1, 2, 2, 3};
__constant__ int PAIR_B[NPAIR] = {1, 2, 3, 4, 2, 3, 4, 3, 4, 4};

__device__ inline unsigned short f2bf(float f) {
    union { float f; uint32_t u; } v; v.f = f;
    uint32_t r = v.u + 0x7fffu + ((v.u >> 16) & 1u);   // RNE for normal values
    return (unsigned short)(r >> 16);
}

__device__ inline void load_lds16(const void* g, void* l) {
    // async global->LDS, 16B/lane; dest = wave-uniform base + lane*16
    __builtin_amdgcn_global_load_lds((const __attribute__((address_space(1))) void*)g,
                                     (__attribute__((address_space(3))) void*)l, 16, 0, 0);
}

// ---------------- Kernel 1a: router v7 — coalesced LDS-staged x ---------------------
// Round-4 diagnosis: after removing atomics, router's residual cost is the x gather:
// lane stride 1536B -> 64 lines per wave-load, ~25M scattered transactions. v7 stages
// x per 64-token block in 3 chunks of 128 floats: loads are 512B-contiguous per 32
// lanes (fully coalesced); LDS row stride 129 makes compute reads bank-free
// ((lane+j)%32, 2-way only). fp64 dot / strict-> top-2 / ballot histogram unchanged
// (c-partition across waves differs only in fp64 summation grouping, err ~1e-16).
__global__ __launch_bounds__(256) void router_kernel(const float* __restrict__ x,
                                                     const float* __restrict__ Wg,
                                                     int* __restrict__ blkcnt,
                                                     int* __restrict__ tmeta,
                                                     float2* __restrict__ tgate) {
    __shared__ __align__(16) float  xs[64 * 129];        // 32.25 KB chunk buffer
    __shared__ __align__(16) float  wgs[CDIM * 8];       // padded stride 8, 12 KB
    __shared__ __align__(16) double part[4 * 64 * NEXP]; // 10 KB
    __shared__ __align__(16) double lg[64 * NEXP];       // 2.5 KB   (total ~56.8 KB)
    int t = threadIdx.x, lane = t & 63, w = t >> 6;
    int tok0 = blockIdx.x * 64;

    for (int i = t; i < CDIM * NEXP; i += 256) wgs[(i / NEXP) * 8 + (i % NEXP)] = Wg[i];

    int lrow = t >> 5, loff = (t & 31) * 4;              // 32 lanes cover one 512B row-chunk
    double p0 = 0, p1 = 0, p2 = 0, p3 = 0, p4 = 0;
    #pragma unroll
    for (int ch = 0; ch < 3; ++ch) {
        __syncthreads();                                 // prev-chunk readers done (+wgs at ch=0)
        #pragma unroll
        for (int r8 = 0; r8 < 8; ++r8) {
            int row = r8 * 8 + lrow;
            float4 v = *(const float4*)&x[(size_t)(tok0 + row) * CDIM + ch * 128 + loff];
            float* d = &xs[row * 129 + loff];
            d[0] = v.x; d[1] = v.y; d[2] = v.z; d[3] = v.w;
        }
        __syncthreads();                                 // chunk staged
        const float* xr = &xs[lane * 129 + w * 32];      // bank (lane+j)%32 -> conflict-free
        #pragma unroll
        for (int j = 0; j < 32; ++j) {
            int c = ch * 128 + w * 32 + j;               // wave-uniform -> wgs broadcast
            float4 w03 = *(const float4*)&wgs[c * 8];
            float  w4  = wgs[c * 8 + 4];
            double xd = (double)xr[j];
            p0 += xd * w03.x; p1 += xd * w03.y; p2 += xd * w03.z;
            p3 += xd * w03.w; p4 += xd * w4;
        }
    }
    double* pr = &part[(w * 64 + lane) * NEXP];
    pr[0] = p0; pr[1] = p1; pr[2] = p2; pr[3] = p3; pr[4] = p4;
    __syncthreads();

    for (int item = t; item < 64 * NEXP; item += 256) {
        lg[item] = part[item] + part[320 + item] + part[640 + item] + part[960 + item];
    }
    __syncthreads();

    if (t < 64) {                                        // wave 0: whole block's tokens
        double pa[NEXP];
        #pragma unroll
        for (int e = 0; e < NEXP; ++e) pa[e] = lg[t * NEXP + e];
        int i0 = 0; double m0v = pa[0];
        #pragma unroll
        for (int e = 1; e < NEXP; ++e) if (pa[e] > m0v) { m0v = pa[e]; i0 = e; }  // strict >: lax.top_k ties
        int i1 = -1; double m1v = -1e300;
        #pragma unroll
        for (int e = 0; e < NEXP; ++e) if (e != i0 && pa[e] > m1v) { m1v = pa[e]; i1 = e; }
        float d  = (float)(m1v - m0v);
        float e1 = expf(d);
        float inv = 1.0f / (1.0f + e1);                  // gate of i0; gate of i1 = e1*inv

        int a  = i0 < i1 ? i0 : i1;
        int b2 = i0 < i1 ? i1 : i0;
        int p  = a * 4 - ((a * (a - 1)) >> 1) + (b2 - a - 1);
        float ga = (a == i0) ? inv : e1 * inv;           // gate of lower-indexed expert
        float gb = (a == i0) ? e1 * inv : inv;

        unsigned long long below = (1ull << lane) - 1ull;
        int myrank = 0, myh = 0;
        #pragma unroll
        for (int e = 0; e < NPAIR; ++e) {
            unsigned long long mask = __ballot(p == e);
            if (p == e)    myrank = (int)__popcll(mask & below);
            if (lane == e) myh    = (int)__popcll(mask);
        }
        tmeta[tok0 + lane] = p | (myrank << 8);          // p<10, rank<64
        tgate[tok0 + lane] = make_float2(ga, gb);
        if (lane < NPAIR) blkcnt[lane * NBLK + blockIdx.x] = myh;
    }
}

// ---------------- Kernel 1b: per-pair exclusive prefix over 1024 block counts -------
__global__ __launch_bounds__(256) void scan_kernel(const int* __restrict__ blkcnt,
                                                   int* __restrict__ bbase,
                                                   int* __restrict__ cnt) {
    __shared__ int wsum[4];
    int p = blockIdx.x, t = threadIdx.x, lane = t & 63, w = t >> 6;
    int4 v = ((const int4*)(blkcnt + p * NBLK))[t];      // blocks 4t..4t+3
    int s0 = v.x, s1 = s0 + v.y, s2 = s1 + v.z, s3 = s2 + v.w;
    int ws = s3;                                         // wave-inclusive scan of totals
    #pragma unroll
    for (int d = 1; d < 64; d <<= 1) {
        int o = __shfl_up(ws, d);
        if (lane >= d) ws += o;
    }
    if (lane == 63) wsum[w] = ws;
    __syncthreads();
    int woff = 0;
    for (int k = 0; k < w; ++k) woff += wsum[k];
    int excl = woff + ws - s3;                           // exclusive prefix before block 4t
    int4 b; b.x = excl; b.y = excl + s0; b.z = excl + s1; b.w = excl + s2;
    ((int4*)(bbase + p * NBLK))[t] = b;
    if (t == 255) cnt[p] = excl + s3;
}

// ---------------- Kernel 1c: scatter token ids to bucket positions ------------------
__global__ __launch_bounds__(256) void scatter_kernel(const int* __restrict__ tmeta,
                                                      const int* __restrict__ bbase,
                                                      int* __restrict__ bidx) {
    int tok = blockIdx.x * 256 + threadIdx.x;
    int meta = tmeta[tok];
    int p = meta & 255, rank = meta >> 8;
    int pos = bbase[p * NBLK + (tok >> 6)] + rank;
    if (pos < CAP) bidx[p * CAP + pos] = tok;
}

// ---------------- Kernel 2: We[e][c][d] fp32 -> WeT[e][d][c] bf16 (tiled transpose) --
__global__ __launch_bounds__(256) void convert_we(const float* __restrict__ We,
                                                  unsigned short* __restrict__ WeT) {
    __shared__ float tile[64][65];
    int e  = blockIdx.z;
    int c0 = blockIdx.x * 64, d0 = blockIdx.y * 64;
    int t  = threadIdx.x;
    const float* src = We + (size_t)e * WE_STRIDE;
    int dr = t & 15, cr = t >> 4;
    for (int s = 0; s < 64; s += 16) {
        float4 v = *(const float4*)&src[(size_t)(c0 + cr + s) * CDIM + d0 + dr * 4];
        tile[cr + s][dr * 4 + 0] = v.x;
        tile[cr + s][dr * 4 + 1] = v.y;
        tile[cr + s][dr * 4 + 2] = v.z;
        tile[cr + s][dr * 4 + 3] = v.w;
    }
    __syncthreads();
    unsigned short* dst = WeT + (size_t)e * WE_STRIDE;
    int c4 = t & 15, drow = t >> 4;
    for (int s = 0; s < 64; s += 16) {
        int d = drow + s;
        ushort4 o;
        o.x = f2bf(tile[c4 * 4 + 0][d]);
        o.y = f2bf(tile[c4 * 4 + 1][d]);
        o.z = f2bf(tile[c4 * 4 + 2][d]);
        o.w = f2bf(tile[c4 * 4 + 3][d]);
        *(ushort4*)&dst[(size_t)(d0 + d) * CDIM + c0 + c4 * 4] = o;
    }
}

// ---------------- Kernel 3: grouped gathered GEMM, 128x128, counted-vmcnt pipeline --
// Round-4 diagnosis: 74.5us vs 15.5us MFMA floor; ~80% stall. __syncthreads' implicit
// vmcnt(0) drained the B-DMA issued only one phase earlier (the m97-structure stall).
// v3 (T4): raw s_barrier + counted vmcnt; B triple-buffered with a 2-phase DMA lead.
// Per-region issue = {x(2 ops), B-DMA(2 ops)}; at barrier kc, ops after B[kc] are
// {x[kc+1],B[kc+1]} = 4 -> s_waitcnt vmcnt(4) guarantees B[kc] landed while keeping
// 4 prefetch ops in flight across the barrier. vmcnt(0) only at kc=0 and kc=11.
// Hazard audit: B[kc+2] issued AFTER barrier kc into buf (kc-1)%3 whose readers all
// finished before that barrier; A stays double-buffered; epilogue __syncthreads
// drains everything before S is reused for gates.
__global__ __launch_bounds__(512, 4) void moe_kernel(const float* __restrict__ x,
                                                     const unsigned short* __restrict__ WeT,
                                                     const int* __restrict__ cnt,
                                                     const int* __restrict__ bidx,
                                                     const float2* __restrict__ tgate,
                                                     const float* __restrict__ be,
                                                     float* __restrict__ out) {
    // grid 1920 = 8*240: bijective XCD-chunk swizzle
    int bh  = blockIdx.x;
    int bid = (bh & 7) * 240 + (bh >> 3);
    int pq  = bid / 3;                    // p*64 + mt
    int nt  = bid - pq * 3;
    int p   = pq >> 6;
    int mt  = pq & 63;

    int nct = cnt[p];
    int m0  = mt * 128;
    if (m0 >= nct) return;                // block-uniform early exit (before any barrier)
    int valid = nct - m0; if (valid > 128) valid = 128;

    int ea = PAIR_A[p], eb = PAIR_B[p];
    int n0 = nt * 128;
    int t = threadIdx.x, lane = t & 63, wid = t >> 6;
    int wm = wid >> 1, wn = wid & 1;      // 4(m) x 2(n) waves -> wave tile 32x64
    int q = lane >> 4, cc = lane & 15;

    // granules (16B): A dbuf 0..1023 (512/buf), B tribuf 1024..4095 (1024/buf) = 64 KB
    __shared__ __align__(16) unsigned short S[4096 * 8];

    floatx4 acc[2][2][4];                 // [expert a/b][m-sub][n-sub]
    #pragma unroll
    for (int e = 0; e < 2; ++e)
        #pragma unroll
        for (int i = 0; i < 2; ++i)
            #pragma unroll
            for (int j = 0; j < 4; ++j)
                acc[e][i][j] = (floatx4){0.0f, 0.0f, 0.0f, 0.0f};

    // B staging via DMA: 1024 granules/kc, 2/thread (expert a and expert b halves)
    int rrow = t >> 2, gp = t & 3;
    int gl = (gp - (rrow >> 1)) & 3;      // conflict-free k-granule perm (verified)
    const unsigned short* bsrcA = WeT + (size_t)ea * WE_STRIDE + (size_t)(n0 + rrow) * CDIM + gl * 8;
    const unsigned short* bsrcB = WeT + (size_t)eb * WE_STRIDE + (size_t)(n0 + rrow) * CDIM + gl * 8;
    int bdstA = wid * 64;                 // granule within B buf (+lane via DMA)
    int bdstB = 512 + wid * 64;

    // A staging: thread -> (gathered row, 16B piece), swizzled dest granule
    int srow = t >> 2, sp = t & 3;
    int arow = m0 + (srow < valid ? srow : valid - 1);   // clamp: ragged last tile
    int gi = bidx[p * CAP + arow];
    const float* xrow = x + (size_t)gi * CDIM + sp * 8;
    int agr = 4 * srow + ((sp + (srow >> 1)) & 3);       // + buf*512

    // fragment read bases (loop-invariant perm: (row>>1)&3 == (cc>>1)&3)
    int perm = (q + (cc >> 1)) & 3;
    int a_gr = 4 * (wm * 32 + cc) + perm;                // + 64*i + buf*512
    int b_gr = 4 * (wn * 64 + cc) + perm;                // + 512*e + 64*j + bufbase

    // prologue: x0,x1 regs (issued BEFORE the B DMAs); DMA B0->buf0, B1->buf1
    float4 xreg[2][2];
    xreg[0][0] = *(const float4*)(xrow);
    xreg[0][1] = *(const float4*)(xrow + 4);
    xreg[1][0] = *(const float4*)(xrow + 32);
    xreg[1][1] = *(const float4*)(xrow + 36);
    load_lds16(bsrcA,      S + (size_t)(1024 + bdstA) * 8);
    load_lds16(bsrcB,      S + (size_t)(1024 + bdstB) * 8);
    load_lds16(bsrcA + 32, S + (size_t)(2048 + bdstA) * 8);
    load_lds16(bsrcB + 32, S + (size_t)(2048 + bdstB) * 8);

    #pragma unroll
    for (int kc = 0; kc < 12; ++kc) {
        int buf = kc & 1;                 // A buffer
        int bb  = kc - (kc / 3) * 3;      // B buffer (kc%3, constant-folded)
        // convert x[kc] -> As[buf]
        float4 a0 = xreg[buf][0], a1 = xreg[buf][1];
        short8 av;
        av[0] = f2bf(a0.x); av[1] = f2bf(a0.y); av[2] = f2bf(a0.z); av[3] = f2bf(a0.w);
        av[4] = f2bf(a1.x); av[5] = f2bf(a1.y); av[6] = f2bf(a1.z); av[7] = f2bf(a1.w);
        *(short8*)&S[(size_t)(buf * 512 + agr) * 8] = av;

        // counted-vmcnt barrier: B[kc] landed, {x[kc+1],B[kc+1]} stay in flight
        if (kc == 0 || kc == 11) {
            asm volatile("s_waitcnt vmcnt(0) lgkmcnt(0)" ::: "memory");
        } else {
            asm volatile("s_waitcnt vmcnt(4) lgkmcnt(0)" ::: "memory");
        }
        __builtin_amdgcn_s_barrier();
        __builtin_amdgcn_sched_barrier(0);

        if (kc < 10) {                    // issue kc+2 prefetch (x first, then B-DMA)
            int k2 = (kc + 2) * 32;
            int nb = (kc + 2) % 3;
            xreg[buf][0] = *(const float4*)(xrow + k2);
            xreg[buf][1] = *(const float4*)(xrow + k2 + 4);
            load_lds16(bsrcA + k2, S + (size_t)(1024 + nb * 1024 + bdstA) * 8);
            load_lds16(bsrcB + k2, S + (size_t)(1024 + nb * 1024 + bdstB) * 8);
        }

        int ao = buf * 512, bo = 1024 + bb * 1024;
        short8 af0 = *(const short8*)&S[(size_t)(ao + a_gr) * 8];
        short8 af1 = *(const short8*)&S[(size_t)(ao + a_gr + 64) * 8];
        #pragma unroll
        for (int e = 0; e < 2; ++e) {
            #pragma unroll
            for (int j = 0; j < 4; ++j) {
                short8 bf = *(const short8*)&S[(size_t)(bo + b_gr + e * 512 + j * 64) * 8];
                acc[e][0][j] = __builtin_amdgcn_mfma_f32_16x16x32_bf16(af0, bf, acc[e][0][j], 0, 0, 0);
                acc[e][1][j] = __builtin_amdgcn_mfma_f32_16x16x32_bf16(af1, bf, acc[e][1][j], 0, 0, 0);
            }
        }
    }

    // ---- epilogue: gates+indices to LDS, combine + bias + leaky, scatter store -----
    __syncthreads();                      // full drain before reusing S
    float2* Gp = (float2*)S;                             // 128 * 8B = 1 KB
    int*    Ip = (int*)((char*)S + 1024);                // 128 * 4B
    if (t < 128) {
        int rr = m0 + (t < valid ? t : valid - 1);
        int gid = bidx[p * CAP + rr];
        Ip[t] = gid;
        Gp[t] = tgate[gid];
    }
    float ba_[4], bb_[4];
    #pragma unroll
    for (int j = 0; j < 4; ++j) {
        int oc = n0 + wn * 64 + j * 16 + cc;
        ba_[j] = be[ea * CDIM + oc];
        bb_[j] = be[eb * CDIM + oc];
    }
    __syncthreads();

    #pragma unroll
    for (int i = 0; i < 2; ++i) {
        #pragma unroll
        for (int rr4 = 0; rr4 < 4; ++rr4) {
            int trow = wm * 32 + i * 16 + q * 4 + rr4;   // C/D: col=cc, row=q*4+rr4
            if (trow < valid) {
                float2 g = Gp[trow];
                int gid  = Ip[trow];
                #pragma unroll
                for (int j = 0; j < 4; ++j) {
                    int oc = n0 + wn * 64 + j * 16 + cc;
                    float v = g.x * (acc[0][i][j][rr4] + ba_[j])
                            + g.y * (acc[1][i][j][rr4] + bb_[j]);
                    v = v > 0.0f ? v : 0.01f * v;
                    out[(size_t)gid * CDIM + oc] = v;
                }
            }
        }
    }
}

extern "C" void kernel_launch(void* const* d_in, const int* in_sizes, int n_in,
                              void* d_out, int out_size, void* d_ws, size_t ws_size,
                              hipStream_t stream) {
    const float* x  = (const float*)d_in[0];
    const float* Wg = (const float*)d_in[1];
    const float* We = (const float*)d_in[2];
    const float* be = (const float*)d_in[3];
    float* out = (float*)d_out;

    // ws layout (16B-aligned sections), total ~2.67 MB:
    //   cnt[10]            @ 0       (pad 256)
    //   bidx  10*8192*4    @ 256         = 327680
    //   blkcnt 10*1024*4   @ 327936      = 40960
    //   bbase  10*1024*4   @ 368896      = 40960
    //   tmeta  65536*4     @ 409856      = 262144
    //   tgate  65536*8     @ 672000      = 524288
    //   WeT    5*384*384*2 @ 1196288     = 1474560
    char* ws = (char*)d_ws;
    int*            cnt    = (int*)ws;
    int*            bidx   = (int*)(ws + 256);
    int*            blkcnt = (int*)(ws + 327936);
    int*            bbase  = (int*)(ws + 368896);
    int*            tmeta  = (int*)(ws + 409856);
    float2*         tgate  = (float2*)(ws + 672000);
    unsigned short* WeT    = (unsigned short*)(ws + 1196288);

    router_kernel<<<NBLK, 256, 0, stream>>>(x, Wg, blkcnt, tmeta, tgate);
    scan_kernel<<<NPAIR, 256, 0, stream>>>(blkcnt, bbase, cnt);
    scatter_kernel<<<TOKENS / 256, 256, 0, stream>>>(tmeta, bbase, bidx);
    convert_we<<<dim3(6, 6, 5), 256, 0, stream>>>(We, WeT);
    moe_kernel<<<NPAIR * 64 * 3, 512, 0, stream>>>(x, WeT, cnt, bidx, tgate, be, out);
}